// Round 7
// baseline (5343.216 us; speedup 1.0000x reference)
//
#include <hip/hip_runtime.h>
#include <hip/hip_bf16.h>
#include <stdint.h>
#include <math.h>

// Problem constants (fixed by the reference)
#define SEQ    2048
#define EMB    1024
#define HID    1024
#define G4     4096      // 4*HID
#define NEMO   16
#define NLAB   7

// Fused-kernel role partition (dispatch order == dependency order):
//   bid [0,128)    : C-GEMM tiles  (16 row-blocks x 8 col-blocks)
//   bid [128,640)  : G-GEMM tiles  (16 row-blocks x 32 col-blocks), gated on progC
//   bid [640,768)  : LSTM persistent scan (R1 structure), gated on progG
// Producer->consumer: progC[16]/progG[16] release-adds after fence; consumers
// acquire-poll with ONE thread + block barrier. A-matrix (C) and Gin values are
// read via agent-scope relaxed atomics (coherent at the MALL, same mechanism as
// the proven htag exchange). 768 blocks x 256 thr, 16KB LDS -> 3 blocks/CU,
// fully co-resident; ordering alone already guarantees no deadlock.
#define NB_C    128
#define NB_G    512
#define NB_LSTM 128
#define CBLK_PER_ROW 8u
#define GBLK_PER_ROW 32u

__device__ __forceinline__ float sigf(float x) { return 1.0f / (1.0f + expf(-x)); }

// 16B coherent load as 2x u64 agent-relaxed atomics (reads at coherence point).
__device__ __forceinline__ float4 aload16(const float* p)
{
    unsigned long long u0 = __hip_atomic_load((const unsigned long long*)p,
                                              __ATOMIC_RELAXED, __HIP_MEMORY_SCOPE_AGENT);
    unsigned long long u1 = __hip_atomic_load((const unsigned long long*)(p + 2),
                                              __ATOMIC_RELAXED, __HIP_MEMORY_SCOPE_AGENT);
    return make_float4(__uint_as_float((unsigned)u0),
                       __uint_as_float((unsigned)(u0 >> 32)),
                       __uint_as_float((unsigned)u1),
                       __uint_as_float((unsigned)(u1 >> 32)));
}

// ---------------- k_init: emoji average + htag/prog reset ----------------
__global__ void k_init(const int* __restrict__ emoji_ids,
                       const float* __restrict__ emoji_emb,
                       float* __restrict__ eave,
                       unsigned long long* __restrict__ htag,
                       unsigned* __restrict__ prog)
{
    int t = threadIdx.x;
    int ids[NEMO];
#pragma unroll
    for (int n = 0; n < NEMO; ++n) ids[n] = emoji_ids[n];
    for (int e = t; e < EMB; e += 256) {
        float s = 0.f;
#pragma unroll
        for (int n = 0; n < NEMO; ++n) s += emoji_emb[(size_t)ids[n] * EMB + e];
        eave[e] = s * (1.0f / 16.0f);
    }
    // htag[2][HID]: tag=0, value=0.0f  (h_{-1} = zeros, parity-1 buffer)
    for (int i = t; i < 2 * HID; i += 256) htag[i] = 0ull;
    if (t < 32) prog[t] = 0u;   // progC[16] + progG[16]
}

// ---------------- k_cvec: cvec = comb_W[:,1024:] @ eave + comb_b ----------------
__global__ void k_cvec(const float* __restrict__ combW,
                       const float* __restrict__ combB,
                       const float* __restrict__ eave,
                       float* __restrict__ cvec)
{
    int gw   = (blockIdx.x * 256 + threadIdx.x) >> 6;
    int lane = threadIdx.x & 63;
#pragma unroll
    for (int rr = 0; rr < 4; ++rr) {
        int r = gw * 4 + rr;
        const float* wrow = combW + (size_t)r * 2048 + 1024;
        float s = 0.f;
        for (int k = lane; k < EMB; k += 64) s = fmaf(wrow[k], eave[k], s);
#pragma unroll
        for (int off = 1; off < 64; off <<= 1) s += __shfl_xor(s, off);
        if (lane == 0) cvec[r] = s + combB[r];
    }
}

// ---------------- k_fused: C-GEMM + G-GEMM + LSTM scan in one launch ----------------
__global__ __launch_bounds__(256, 1) void k_fused(
    const int*   sent_ids,
    const float* word_emb,
    const float* comb_W,
    const float* cvec,
    float*       C,
    const float* W_ih,
    const float* b_ih,
    const float* b_hh,
    float*       G,       // Gin [2048][4096]
    const float* Whh,     // [4096][1024]
    unsigned long long* htag,
    unsigned*    progC,
    unsigned*    progG)
{
    __shared__ float smem[4096];   // 16 KB, carved per role
    const int bid = blockIdx.x;
    const int t   = threadIdx.x;

    if (bid < NB_C + NB_G) {
        // =========== GEMM roles: one shared body, role-selected parameters =======
        // O[m][n] = sum_k Arow(m)[k] * Bm[n*bstride + k] + bias1[n] (+bias2) (+relu)
        const float* Asrc; const int* ids;
        const float* Bm; int bstride;
        const float* bias1; const float* bias2;
        float* O; int N; int relu; int bx, by;
        if (bid < NB_C) {
            // C = relu( gather(word_emb, sent_ids) @ comb_W[:, :1024]^T + cvec )
            by = bid >> 3; bx = bid & 7;
            Asrc = nullptr; ids = sent_ids;
            Bm = comb_W; bstride = 2048;
            bias1 = cvec; bias2 = nullptr;
            O = C; N = EMB; relu = 1;
        } else {
            // G = C @ W_ih^T + b_ih + b_hh   (gated on C row-block readiness)
            const int idx = bid - NB_C;
            by = idx >> 5; bx = idx & 31;
            if (t == 0) {
                while (__hip_atomic_load(progC + by, __ATOMIC_ACQUIRE,
                                         __HIP_MEMORY_SCOPE_AGENT) != CBLK_PER_ROW) {}
            }
            __syncthreads();
            Asrc = C; ids = nullptr;
            Bm = W_ih; bstride = 1024;
            bias1 = b_ih; bias2 = b_hh;
            O = G; N = G4; relu = 0;
        }

        float* As_ = smem;          // [16][128]
        float* Bs_ = smem + 2048;   // [16][128]
        const int row0 = by * 128;
        const int col0 = bx * 128;
        const int lr = t >> 2;      // 0..63: staging row
        const int kq = t & 3;       // 0..3 : k quad
        const float *ar0, *ar1;
        if (ids) {
            ar0 = word_emb + (size_t)ids[row0 + lr]      * 1024;
            ar1 = word_emb + (size_t)ids[row0 + lr + 64] * 1024;
        } else {
            ar0 = Asrc + (size_t)(row0 + lr)      * 1024;
            ar1 = Asrc + (size_t)(row0 + lr + 64) * 1024;
        }
        const float* br0 = Bm + (size_t)(col0 + lr)      * bstride;
        const float* br1 = Bm + (size_t)(col0 + lr + 64) * bstride;
        const int tx = t & 15, ty = t >> 4;

        float acc[8][8];
#pragma unroll
        for (int i = 0; i < 8; ++i)
#pragma unroll
            for (int j = 0; j < 8; ++j) acc[i][j] = 0.f;

        for (int k0 = 0; k0 < 1024; k0 += 16) {
            // A loads are coherent (C is produced in-kernel); B = static weights.
            float4 a0 = aload16(ar0 + k0 + kq * 4);
            float4 a1 = aload16(ar1 + k0 + kq * 4);
            float4 b0 = *(const float4*)(br0 + k0 + kq * 4);
            float4 b1 = *(const float4*)(br1 + k0 + kq * 4);
            __syncthreads();
            {
                const float* pa0 = &a0.x; const float* pa1 = &a1.x;
                const float* pb0 = &b0.x; const float* pb1 = &b1.x;
#pragma unroll
                for (int e = 0; e < 4; ++e) {
                    As_[(kq * 4 + e) * 128 + lr]      = pa0[e];
                    As_[(kq * 4 + e) * 128 + lr + 64] = pa1[e];
                    Bs_[(kq * 4 + e) * 128 + lr]      = pb0[e];
                    Bs_[(kq * 4 + e) * 128 + lr + 64] = pb1[e];
                }
            }
            __syncthreads();
#pragma unroll
            for (int kk = 0; kk < 16; ++kk) {
                float af[8], bf[8];
                *(float4*)(af)     = *(const float4*)&As_[kk * 128 + ty * 8];
                *(float4*)(af + 4) = *(const float4*)&As_[kk * 128 + ty * 8 + 4];
                *(float4*)(bf)     = *(const float4*)&Bs_[kk * 128 + tx * 8];
                *(float4*)(bf + 4) = *(const float4*)&Bs_[kk * 128 + tx * 8 + 4];
#pragma unroll
                for (int i = 0; i < 8; ++i)
#pragma unroll
                    for (int j = 0; j < 8; ++j)
                        acc[i][j] = fmaf(af[i], bf[j], acc[i][j]);
            }
        }
        float bv[8];
        *(float4*)(bv)     = *(const float4*)&bias1[col0 + tx * 8];
        *(float4*)(bv + 4) = *(const float4*)&bias1[col0 + tx * 8 + 4];
        if (bias2) {
            float b2[8];
            *(float4*)(b2)     = *(const float4*)&bias2[col0 + tx * 8];
            *(float4*)(b2 + 4) = *(const float4*)&bias2[col0 + tx * 8 + 4];
#pragma unroll
            for (int j = 0; j < 8; ++j) bv[j] += b2[j];
        }
#pragma unroll
        for (int i = 0; i < 8; ++i) {
            int m = row0 + ty * 8 + i;
            float o[8];
#pragma unroll
            for (int j = 0; j < 8; ++j) {
                float v = acc[i][j] + bv[j];
                o[j] = relu ? fmaxf(v, 0.f) : v;
            }
            *(float4*)&O[(size_t)m * N + col0 + tx * 8]     = *(float4*)(o);
            *(float4*)&O[(size_t)m * N + col0 + tx * 8 + 4] = *(float4*)(o + 4);
        }

        __syncthreads();   // all tile stores issued
        if (t == 0) {
            __threadfence();   // write-back to coherence point
            if (bid < NB_C)
                __hip_atomic_fetch_add(progC + by, 1u, __ATOMIC_RELEASE,
                                       __HIP_MEMORY_SCOPE_AGENT);
            else
                __hip_atomic_fetch_add(progG + by, 1u, __ATOMIC_RELEASE,
                                       __HIP_MEMORY_SCOPE_AGENT);
        }
        return;
    }

    // =========== LSTM role: R1 structure (measured optimum) + Gin gate ===========
    const int b    = bid - (NB_C + NB_G);   // 0..127, owns units [8b, 8b+8)
    const int lane = t & 63;
    const int wv   = t >> 6;                // wave id 0..3

    // W_hh fragment: 8 rows (wv+4i), cols [lane*16, lane*16+16)
    float w[8][16];
#pragma unroll
    for (int i = 0; i < 8; ++i) {
        int r = wv + 4 * i;
        int grow = ((r >> 3) << 10) + (b << 3) + (r & 7);
        const float4* p = (const float4*)(Whh + (size_t)grow * HID + lane * 16);
#pragma unroll
        for (int q = 0; q < 4; ++q) {
            float4 a = p[q];
            w[i][4 * q + 0] = a.x; w[i][4 * q + 1] = a.y;
            w[i][4 * q + 2] = a.z; w[i][4 * q + 3] = a.w;
        }
    }

    float4* hl4 = (float4*)smem;             // 256 float4 (4 KB)
    float*  red = smem + 1024;               // 32*72
    float*  gat = smem + 1024 + 2304;        // 32
    float*  cst = smem + 1024 + 2304 + 32;   // 8
    if (t < 8) cst[t] = 0.f;

    const int s_j4 = t & 3, s_col = t >> 2;
    const int rr = t >> 3, kk = t & 7;
    const int growR = ((rr >> 3) << 10) + (b << 3) + (rr & 7);
    unsigned long long* myslots0 = htag + 4 * t;

    int rb_ready = 0;   // watermark: Gin row-blocks [0, rb_ready*128) complete

    for (int s = 0; s < SEQ; ++s) {
        // gate on Gin row-block readiness: 1 poller + barrier, 16 times total
        const int rb = s >> 7;
        if (rb >= rb_ready) {
            if (t == 0) {
                while (__hip_atomic_load(progG + rb, __ATOMIC_ACQUIRE,
                                         __HIP_MEMORY_SCOPE_AGENT) != GBLK_PER_ROW) {}
            }
            __syncthreads();
            rb_ready = rb + 1;
        }

        // this step's G_in rows — coherent relaxed atomic (produced in-kernel)
        float gval = 0.f;
        if (kk == 0) {
            unsigned gu = __hip_atomic_load(
                (const unsigned*)(G + (size_t)s * G4 + growR),
                __ATOMIC_RELAXED, __HIP_MEMORY_SCOPE_AGENT);
            gval = __uint_as_float(gu);
        }

        // poll h_{s-1}: 4 tagged slots per thread
        unsigned long long* src = myslots0 + (size_t)(((unsigned)(s + 1)) & 1u) * HID;
        const unsigned expw = (unsigned)s;
        unsigned long long v0, v1, v2, v3;
        for (;;) {
            v0 = __hip_atomic_load(src + 0, __ATOMIC_RELAXED, __HIP_MEMORY_SCOPE_AGENT);
            v1 = __hip_atomic_load(src + 1, __ATOMIC_RELAXED, __HIP_MEMORY_SCOPE_AGENT);
            v2 = __hip_atomic_load(src + 2, __ATOMIC_RELAXED, __HIP_MEMORY_SCOPE_AGENT);
            v3 = __hip_atomic_load(src + 3, __ATOMIC_RELAXED, __HIP_MEMORY_SCOPE_AGENT);
            int ok = ((unsigned)(v0 >> 32) == expw) & ((unsigned)(v1 >> 32) == expw) &
                     ((unsigned)(v2 >> 32) == expw) & ((unsigned)(v3 >> 32) == expw);
            if (__all(ok)) break;
        }
        hl4[s_j4 * 64 + s_col] = make_float4(
            __uint_as_float((unsigned)v0), __uint_as_float((unsigned)v1),
            __uint_as_float((unsigned)v2), __uint_as_float((unsigned)v3));
        __syncthreads();   // S1: h staged

        float hf[16];
#pragma unroll
        for (int q = 0; q < 4; ++q) {
            float4 hv = hl4[q * 64 + lane];
            hf[4 * q + 0] = hv.x; hf[4 * q + 1] = hv.y;
            hf[4 * q + 2] = hv.z; hf[4 * q + 3] = hv.w;
        }
        float p[8];
#pragma unroll
        for (int i = 0; i < 8; ++i) p[i] = 0.f;
#pragma unroll
        for (int j = 0; j < 16; ++j)
#pragma unroll
            for (int i = 0; i < 8; ++i)
                p[i] = fmaf(w[i][j], hf[j], p[i]);
#pragma unroll
        for (int i = 0; i < 8; ++i) red[(wv + 4 * i) * 72 + lane] = p[i];
        __syncthreads();   // S2: partials written

        float rs = 0.f;
#pragma unroll
        for (int j = 0; j < 8; ++j) rs += red[rr * 72 + j * 8 + kk];
        rs += __shfl_xor(rs, 1);
        rs += __shfl_xor(rs, 2);
        rs += __shfl_xor(rs, 4);
        if (kk == 0) gat[rr] = rs + gval;
        __syncthreads();   // S3: gates assembled

        if (t < 8) {
            float gi = gat[t], gf = gat[8 + t], gg = gat[16 + t], go = gat[24 + t];
            float c = sigf(gf) * cst[t] + sigf(gi) * tanhf(gg);
            cst[t] = c;
            float h = sigf(go) * tanhf(c);
            unsigned long long pk =
                ((unsigned long long)(unsigned)(s + 1) << 32) |
                (unsigned long long)__float_as_uint(h);
            __hip_atomic_store(htag + (size_t)(((unsigned)s) & 1u) * HID + b * 8 + t,
                               pk, __ATOMIC_RELAXED, __HIP_MEMORY_SCOPE_AGENT);
        }
        // No trailing barrier: next step's S1/S2 protect all shared buffers.
    }
}

// ---------------- k_out: out = out_W @ h_final + out_b ----------------
__global__ void k_out(const float* __restrict__ outW,
                      const float* __restrict__ outb,
                      const unsigned long long* __restrict__ htag,
                      float* __restrict__ out)
{
    int wv = threadIdx.x >> 6, lane = threadIdx.x & 63;   // 7 waves
    if (wv < NLAB) {
        float s = 0.f;
        for (int k = lane; k < HID; k += 64) {
            float h = __uint_as_float((unsigned)(htag[HID + k] & 0xffffffffULL));
            s = fmaf(outW[wv * HID + k], h, s);
        }
#pragma unroll
        for (int off = 1; off < 64; off <<= 1) s += __shfl_xor(s, off);
        if (lane == 0) out[wv] = s + outb[wv];
    }
}

extern "C" void kernel_launch(void* const* d_in, const int* in_sizes, int n_in,
                              void* d_out, int out_size, void* d_ws, size_t ws_size,
                              hipStream_t stream)
{
    const int*   sent_ids = (const int*)  d_in[0];
    const int*   emo_ids  = (const int*)  d_in[1];
    const float* word_emb = (const float*)d_in[2];
    const float* emo_emb  = (const float*)d_in[3];
    // d_in[4] attn_W, d_in[5] attn_b: unused — softmax over a single logit == 1.0
    const float* comb_W   = (const float*)d_in[6];
    const float* comb_b   = (const float*)d_in[7];
    const float* W_ih     = (const float*)d_in[8];
    const float* W_hh     = (const float*)d_in[9];
    const float* b_ih     = (const float*)d_in[10];
    const float* b_hh     = (const float*)d_in[11];
    const float* out_W    = (const float*)d_in[12];
    const float* out_b    = (const float*)d_in[13];
    float* out = (float*)d_out;

    float* ws   = (float*)d_ws;
    float* eave = ws;                                   // 1024
    float* cvec = ws + 1024;                            // 1024 (pad to 4096)
    float* C    = ws + 4096;                            // 2048*1024
    float* G    = ws + 4096 + (size_t)SEQ * EMB;        // 2048*4096
    unsigned long long* htag =
        (unsigned long long*)(ws + 4096 + (size_t)SEQ * EMB + (size_t)SEQ * G4); // 2*1024 u64
    unsigned* prog  = (unsigned*)(htag + 2 * HID);      // 32 u32
    unsigned* progC = prog;
    unsigned* progG = prog + 16;

    k_init<<<1, 256, 0, stream>>>(emo_ids, emo_emb, eave, htag, prog);
    k_cvec<<<64, 256, 0, stream>>>(comb_W, comb_b, eave, cvec);
    k_fused<<<NB_C + NB_G + NB_LSTM, 256, 0, stream>>>(
        sent_ids, word_emb, comb_W, cvec, C, W_ih, b_ih, b_hh, G, W_hh,
        htag, progC, progG);
    k_out<<<1, 448, 0, stream>>>(out_W, out_b, htag, out);
}